// Round 1
// baseline (564.665 us; speedup 1.0000x reference)
//
#include <hip/hip_runtime.h>

#define FEAT 32

// --- Detect whether the edge_index buffer is stored as int64 (odd int32 words
// all zero for values < 2^31) or int32. Writes flag=1 for int64.
__global__ void detect_int64_kernel(const int* __restrict__ raw, int* flag) {
    __shared__ int nonzero;
    if (threadIdx.x == 0) nonzero = 0;
    __syncthreads();
    int v = raw[2 * threadIdx.x + 1];
    if (v != 0) atomicAdd(&nonzero, 1);
    __syncthreads();
    if (threadIdx.x == 0) *flag = (nonzero == 0) ? 1 : 0;
}

__global__ void convert_idx_kernel(const void* __restrict__ raw, int* __restrict__ out,
                                   const int* __restrict__ flag, int n) {
    int i = blockIdx.x * blockDim.x + threadIdx.x;
    if (i >= n) return;
    if (*flag) {
        out[i] = (int)((const long long*)raw)[i];
    } else {
        out[i] = ((const int*)raw)[i];
    }
}

__global__ void init_deg_kernel(float* __restrict__ deg, int n) {
    int i = blockIdx.x * blockDim.x + threadIdx.x;
    if (i < n) deg[i] = 1.0f;  // self-loop contribution
}

__global__ void count_deg_kernel(const int* __restrict__ dst, float* __restrict__ deg, int e) {
    int i = blockIdx.x * blockDim.x + threadIdx.x;
    if (i < e) atomicAdd(&deg[dst[i]], 1.0f);
}

__global__ void rsqrt_kernel(float* __restrict__ deg, int n) {  // in-place deg -> dis
    int i = blockIdx.x * blockDim.x + threadIdx.x;
    if (i < n) deg[i] = rsqrtf(deg[i]);
}

// Per layer: h = act(in) @ W ;  acc = h * dis^2 + b   (self-loop + bias folded in)
// 256 threads = 8 nodes x 32 feature-lanes.
__global__ void matmul_kernel(const float* __restrict__ in, const float* __restrict__ W,
                              const float* __restrict__ b, const float* __restrict__ dis,
                              float* __restrict__ h, float* __restrict__ acc,
                              int n, int apply_relu) {
    __shared__ float Wl[FEAT * FEAT];
    __shared__ float bl[FEAT];
    int tid = threadIdx.x;
    for (int i = tid; i < FEAT * FEAT; i += 256) Wl[i] = W[i];
    if (tid < FEAT) bl[tid] = b[tid];
    __syncthreads();
    int node = blockIdx.x * 8 + (tid >> 5);
    int j = tid & 31;
    if (node >= n) return;
    float xv = in[node * FEAT + j];
    if (apply_relu) xv = fmaxf(xv, 0.0f);
    float sum = 0.0f;
#pragma unroll
    for (int k = 0; k < FEAT; ++k) {
        float a = __shfl(xv, k, 32);
        sum = fmaf(a, Wl[k * FEAT + j], sum);
    }
    float d = dis[node];
    h[node * FEAT + j] = sum;
    acc[node * FEAT + j] = fmaf(sum, d * d, bl[j]);
}

// One edge per 32 lanes: coalesced 128B gather of h[src], 32 atomicAdds to acc[dst].
__global__ void scatter_kernel(const int* __restrict__ idx, const float* __restrict__ dis,
                               const float* __restrict__ h, float* __restrict__ acc, int e) {
    int t = blockIdx.x * blockDim.x + threadIdx.x;
    int edge = t >> 5;
    int j = t & 31;
    if (edge >= e) return;
    int s = idx[edge];
    int d = idx[e + edge];
    float norm = dis[s] * dis[d];
    atomicAdd(&acc[d * FEAT + j], h[s * FEAT + j] * norm);
}

__global__ void relu_inplace_kernel(float* __restrict__ out, int n4) {
    int i = blockIdx.x * blockDim.x + threadIdx.x;
    if (i < n4) {
        float4 v = ((float4*)out)[i];
        v.x = fmaxf(v.x, 0.0f);
        v.y = fmaxf(v.y, 0.0f);
        v.z = fmaxf(v.z, 0.0f);
        v.w = fmaxf(v.w, 0.0f);
        ((float4*)out)[i] = v;
    }
}

extern "C" void kernel_launch(void* const* d_in, const int* in_sizes, int n_in,
                              void* d_out, int out_size, void* d_ws, size_t ws_size,
                              hipStream_t stream) {
    const float* x = (const float*)d_in[0];
    const void* eidx_raw = d_in[1];
    const float* W1 = (const float*)d_in[2];
    const float* b1 = (const float*)d_in[3];
    const float* W2 = (const float*)d_in[4];
    const float* b2 = (const float*)d_in[5];
    float* out = (float*)d_out;

    const int n = in_sizes[0] / FEAT;      // 100000 nodes
    const int e2 = in_sizes[1];            // 2*E logical elements
    const int e = e2 / 2;                  // 1.6M edges

    // Workspace layout (256B-aligned slices)
    char* ws = (char*)d_ws;
    size_t off = 0;
    int* flag = (int*)(ws + off);  off += 256;
    int* idx = (int*)(ws + off);   off += (size_t)e2 * 4; off = (off + 255) & ~(size_t)255;
    float* dis = (float*)(ws + off); off += (size_t)n * 4; off = (off + 255) & ~(size_t)255;
    float* h = (float*)(ws + off);   off += (size_t)n * FEAT * 4; off = (off + 255) & ~(size_t)255;
    float* acc1 = (float*)(ws + off); off += (size_t)n * FEAT * 4;

    // 0. index format detect + convert to int32
    detect_int64_kernel<<<1, 256, 0, stream>>>((const int*)eidx_raw, flag);
    convert_idx_kernel<<<(e2 + 255) / 256, 256, 0, stream>>>(eidx_raw, idx, flag, e2);

    // 1. degrees -> dis = rsqrt(deg)
    init_deg_kernel<<<(n + 255) / 256, 256, 0, stream>>>(dis, n);
    count_deg_kernel<<<(e + 255) / 256, 256, 0, stream>>>(idx + e, dis, e);
    rsqrt_kernel<<<(n + 255) / 256, 256, 0, stream>>>(dis, n);

    // 2. layer 1: h1 = x@W1 ; acc1 = h1*dis^2 + b1 ; scatter edges
    matmul_kernel<<<(n + 7) / 8, 256, 0, stream>>>(x, W1, b1, dis, h, acc1, n, 0);
    {
        long long threads = (long long)e * 32;
        scatter_kernel<<<(int)((threads + 255) / 256), 256, 0, stream>>>(idx, dis, h, acc1, e);
    }

    // 3. layer 2: h2 = relu(acc1)@W2 ; acc2(d_out) = h2*dis^2 + b2 ; scatter ; relu
    matmul_kernel<<<(n + 7) / 8, 256, 0, stream>>>(acc1, W2, b2, dis, h, out, n, 1);
    {
        long long threads = (long long)e * 32;
        scatter_kernel<<<(int)((threads + 255) / 256), 256, 0, stream>>>(idx, dis, h, out, e);
    }
    relu_inplace_kernel<<<(n * FEAT / 4 + 255) / 256, 256, 0, stream>>>(out, n * FEAT / 4);
}

// Round 2
// 352.127 us; speedup vs baseline: 1.6036x; 1.6036x over previous
//
#include <hip/hip_runtime.h>

#define FEAT 32

// --- Detect whether edge_index is int64 (all odd int32 words zero) or int32.
__global__ void detect_int64_kernel(const int* __restrict__ raw, int* flag) {
    __shared__ int nonzero;
    if (threadIdx.x == 0) nonzero = 0;
    __syncthreads();
    int v = raw[2 * threadIdx.x + 1];
    if (v != 0) atomicAdd(&nonzero, 1);
    __syncthreads();
    if (threadIdx.x == 0) *flag = (nonzero == 0) ? 1 : 0;
}

__device__ __forceinline__ int load_idx(const void* raw, int flag, long long i) {
    return flag ? (int)((const long long*)raw)[i] : ((const int*)raw)[i];
}

__global__ void zero_kernel(int* __restrict__ p, int n) {
    int i = blockIdx.x * blockDim.x + threadIdx.x;
    if (i < n) p[i] = 0;
}

// Histogram of dst == in-degree (excluding self loop).
__global__ void hist_kernel(const void* __restrict__ raw, const int* __restrict__ flag,
                            int* __restrict__ cnt, int e) {
    int i = blockIdx.x * blockDim.x + threadIdx.x;
    if (i >= e) return;
    int d = load_idx(raw, *flag, (long long)e + i);
    atomicAdd(&cnt[d], 1);
}

__global__ void dis_kernel(const int* __restrict__ cnt, float* __restrict__ dis, int n) {
    int i = blockIdx.x * blockDim.x + threadIdx.x;
    if (i < n) dis[i] = rsqrtf((float)cnt[i] + 1.0f);  // +1 self loop
}

// --- 3-phase exclusive scan of cnt -> row_start -------------------------------
__global__ void scan1_kernel(const int* __restrict__ cnt, int* __restrict__ row_start,
                             int* __restrict__ bsum, int n) {
    __shared__ int sd[256];
    int t = threadIdx.x;
    int i = blockIdx.x * 256 + t;
    int v = (i < n) ? cnt[i] : 0;
    sd[t] = v;
    __syncthreads();
    for (int off = 1; off < 256; off <<= 1) {
        int add = (t >= off) ? sd[t - off] : 0;
        __syncthreads();
        sd[t] += add;
        __syncthreads();
    }
    if (i < n) row_start[i] = sd[t] - v;       // exclusive within block
    if (t == 255) bsum[blockIdx.x] = sd[t];    // block total
}

__global__ void scan2_kernel(int* __restrict__ bsum, int nb) {
    __shared__ int sd[512];
    int t = threadIdx.x;
    int v = (t < nb) ? bsum[t] : 0;
    sd[t] = v;
    __syncthreads();
    for (int off = 1; off < 512; off <<= 1) {
        int add = (t >= off) ? sd[t - off] : 0;
        __syncthreads();
        sd[t] += add;
        __syncthreads();
    }
    if (t < nb) bsum[t] = sd[t] - v;           // exclusive block offsets
}

__global__ void scan3_kernel(int* __restrict__ row_start, int* __restrict__ row_next,
                             const int* __restrict__ bsum, int n) {
    int i = blockIdx.x * blockDim.x + threadIdx.x;
    if (i < n) {
        int rs = row_start[i] + bsum[i >> 8];
        row_start[i] = rs;
        row_next[i] = rs;
    }
}

// Bucket edges by dst; record = (src, norm) 8B.
__global__ void fill_kernel(const void* __restrict__ raw, const int* __restrict__ flag,
                            const float* __restrict__ dis, int* __restrict__ row_next,
                            int2* __restrict__ recs, int e) {
    int i = blockIdx.x * blockDim.x + threadIdx.x;
    if (i >= e) return;
    int f = *flag;
    int s = load_idx(raw, f, i);
    int d = load_idx(raw, f, (long long)e + i);
    float norm = dis[s] * dis[d];
    int pos = atomicAdd(&row_next[d], 1);
    recs[pos] = make_int2(s, __float_as_int(norm));
}

// h = act(in) @ W ;  acc = h * dis^2 + b   (self-loop + bias folded in)
__global__ void matmul_kernel(const float* __restrict__ in, const float* __restrict__ W,
                              const float* __restrict__ b, const float* __restrict__ dis,
                              float* __restrict__ h, float* __restrict__ acc,
                              int n, int apply_relu) {
    __shared__ float Wl[FEAT * FEAT];
    __shared__ float bl[FEAT];
    int tid = threadIdx.x;
    for (int i = tid; i < FEAT * FEAT; i += 256) Wl[i] = W[i];
    if (tid < FEAT) bl[tid] = b[tid];
    __syncthreads();
    int node = blockIdx.x * 8 + (tid >> 5);
    int j = tid & 31;
    if (node >= n) return;
    float xv = in[node * FEAT + j];
    if (apply_relu) xv = fmaxf(xv, 0.0f);
    float sum = 0.0f;
#pragma unroll
    for (int k = 0; k < FEAT; ++k) {
        float a = __shfl(xv, k, 32);
        sum = fmaf(a, Wl[k * FEAT + j], sum);
    }
    float d = dis[node];
    h[node * FEAT + j] = sum;
    acc[node * FEAT + j] = fmaf(sum, d * d, bl[j]);
}

// Pull aggregation: 32 lanes per node, 32 records preloaded per coalesced 256B
// load, shfl-broadcast, 4 gathers in flight per step. No atomics.
__global__ void pull_kernel(const int2* __restrict__ recs, const int* __restrict__ row_start,
                            const int* __restrict__ cnt, const float* __restrict__ h,
                            float* __restrict__ acc, int n) {
    int nd = blockIdx.x * 8 + (threadIdx.x >> 5);
    int j = threadIdx.x & 31;
    if (nd >= n) return;
    int start = row_start[nd];
    int deg = cnt[nd];
    float sum = 0.0f;
    for (int c = 0; c < deg; c += 32) {
        int rem = deg - c;
        if (rem > 32) rem = 32;
        int2 rec = (j < rem) ? recs[start + c + j] : make_int2(0, 0);
        int rs = rec.x;
        float rn = __int_as_float(rec.y);
        int m4 = (rem + 3) & ~3;
        for (int k = 0; k < m4; k += 4) {
            int   s0 = __shfl(rs, k,     32); float w0 = __shfl(rn, k,     32);
            int   s1 = __shfl(rs, k + 1, 32); float w1 = __shfl(rn, k + 1, 32);
            int   s2 = __shfl(rs, k + 2, 32); float w2 = __shfl(rn, k + 2, 32);
            int   s3 = __shfl(rs, k + 3, 32); float w3 = __shfl(rn, k + 3, 32);
            float v0 = h[s0 * FEAT + j];
            float v1 = h[s1 * FEAT + j];
            float v2 = h[s2 * FEAT + j];
            float v3 = h[s3 * FEAT + j];
            sum = fmaf(v0, w0, sum);
            sum = fmaf(v1, w1, sum);
            sum = fmaf(v2, w2, sum);
            sum = fmaf(v3, w3, sum);
        }
    }
    acc[nd * FEAT + j] += sum;
}

__global__ void relu_inplace_kernel(float* __restrict__ out, int n4) {
    int i = blockIdx.x * blockDim.x + threadIdx.x;
    if (i < n4) {
        float4 v = ((float4*)out)[i];
        v.x = fmaxf(v.x, 0.0f);
        v.y = fmaxf(v.y, 0.0f);
        v.z = fmaxf(v.z, 0.0f);
        v.w = fmaxf(v.w, 0.0f);
        ((float4*)out)[i] = v;
    }
}

extern "C" void kernel_launch(void* const* d_in, const int* in_sizes, int n_in,
                              void* d_out, int out_size, void* d_ws, size_t ws_size,
                              hipStream_t stream) {
    const float* x = (const float*)d_in[0];
    const void* eidx_raw = d_in[1];
    const float* W1 = (const float*)d_in[2];
    const float* b1 = (const float*)d_in[3];
    const float* W2 = (const float*)d_in[4];
    const float* b2 = (const float*)d_in[5];
    float* out = (float*)d_out;

    const int n = in_sizes[0] / FEAT;   // 100000
    const int e = in_sizes[1] / 2;      // 1600000
    const int nb_scan = (n + 255) / 256;

    // Workspace layout (256B-aligned slices), ~40 MB total
    char* ws = (char*)d_ws;
    size_t off = 0;
    auto alloc = [&](size_t bytes) { char* p = ws + off; off = (off + bytes + 255) & ~(size_t)255; return p; };
    int*   flag      = (int*)  alloc(256);
    int*   cnt       = (int*)  alloc((size_t)n * 4);
    float* dis       = (float*)alloc((size_t)n * 4);
    int*   row_start = (int*)  alloc((size_t)n * 4);
    int*   row_next  = (int*)  alloc((size_t)n * 4);
    int*   bsum      = (int*)  alloc((size_t)nb_scan * 4);
    int2*  recs      = (int2*) alloc((size_t)e * 8);
    float* h         = (float*)alloc((size_t)n * FEAT * 4);
    float* acc1      = (float*)alloc((size_t)n * FEAT * 4);

    const int gN = (n + 255) / 256;
    const int gE = (e + 255) / 256;
    const int gNode = (n + 7) / 8;

    // CSR build
    detect_int64_kernel<<<1, 256, 0, stream>>>((const int*)eidx_raw, flag);
    zero_kernel<<<gN, 256, 0, stream>>>(cnt, n);
    hist_kernel<<<gE, 256, 0, stream>>>(eidx_raw, flag, cnt, e);
    dis_kernel<<<gN, 256, 0, stream>>>(cnt, dis, n);
    scan1_kernel<<<nb_scan, 256, 0, stream>>>(cnt, row_start, bsum, n);
    scan2_kernel<<<1, 512, 0, stream>>>(bsum, nb_scan);
    scan3_kernel<<<gN, 256, 0, stream>>>(row_start, row_next, bsum, n);
    fill_kernel<<<gE, 256, 0, stream>>>(eidx_raw, flag, dis, row_next, recs, e);

    // Layer 1
    matmul_kernel<<<gNode, 256, 0, stream>>>(x, W1, b1, dis, h, acc1, n, 0);
    pull_kernel<<<gNode, 256, 0, stream>>>(recs, row_start, cnt, h, acc1, n);

    // Layer 2
    matmul_kernel<<<gNode, 256, 0, stream>>>(acc1, W2, b2, dis, h, out, n, 1);
    pull_kernel<<<gNode, 256, 0, stream>>>(recs, row_start, cnt, h, out, n);

    relu_inplace_kernel<<<(n * FEAT / 4 + 255) / 256, 256, 0, stream>>>(out, n * FEAT / 4);
}